// Round 10
// baseline (17.709 us; speedup 1.0000x reference)
//
#include <hip/hip_runtime.h>

// Problem constants (from the reference file)
#define GN_NODES   1000000
#define GN_TPB     1024
#define GN_NBLOCKS 512
#define GN_T       (GN_TPB * GN_NBLOCKS)   // 524288 threads total

// Two-kernel, zero-atomic, zero-memset structure (R9), with NBLOCKS 256->512
// as a CLEAN TLP A/B (no atomics to confound it this time):
//   K1 (512x1024): stream-reduce cart+neigh -> 5 block-partial sums ->
//                  plain stores to ws[c*512 + b]  (SoA for coalesced K2 reads)
//   K2 (1x256):    reduce 512 partials per component (2/thread), apply the
//                  affine network once in wave-parallel form, store out[0].

__global__ __launch_bounds__(GN_TPB) void gn_reduce(
    const float* __restrict__ cart,
    const float* __restrict__ neigh,
    float* __restrict__ partials)
{
    const int t   = threadIdx.x;
    const int tid = blockIdx.x * GN_TPB + t;

    float sx = 0.f, sy = 0.f, sz = 0.f, s0 = 0.f, s1 = 0.f;

    // ---- Streaming reduction (R4/R7 loop structure, T-parameterized). ----
    // cart: 3,000,000 floats = 250,000 chunks of 12 floats (4 nodes).
    // Component pattern within a chunk: x y z x y z x y z x y z.
    const float4* cart4 = reinterpret_cast<const float4*>(cart);
    for (int c = tid; c < 250000; c += GN_T) {
        float4 a = cart4[3 * c + 0];
        float4 b = cart4[3 * c + 1];
        float4 d = cart4[3 * c + 2];
        sx += a.x + a.w + b.z + d.y;
        sy += a.y + b.x + b.w + d.z;
        sz += a.z + b.y + d.x + d.w;
    }

    // neigh: 8,000,000 floats = 2,000,000 float4; components alternate 0,1.
    const float4* n4 = reinterpret_cast<const float4*>(neigh);
    int i = tid;
    for (; i + GN_T < 2000000; i += 2 * GN_T) {
        float4 v = n4[i];
        float4 w = n4[i + GN_T];
        s0 += (v.x + v.z) + (w.x + w.z);
        s1 += (v.y + v.w) + (w.y + w.w);
    }
    if (i < 2000000) {
        float4 v = n4[i];
        s0 += v.x + v.z;
        s1 += v.y + v.w;
    }

    // Wave (64-lane) reduce.
    for (int o = 32; o > 0; o >>= 1) {
        sx += __shfl_down(sx, o);
        sy += __shfl_down(sy, o);
        sz += __shfl_down(sz, o);
        s0 += __shfl_down(s0, o);
        s1 += __shfl_down(s1, o);
    }

    __shared__ float red[5][GN_TPB / 64];
    const int wave = t >> 6;
    if ((t & 63) == 0) {
        red[0][wave] = sx; red[1][wave] = sy; red[2][wave] = sz;
        red[3][wave] = s0; red[4][wave] = s1;
    }
    __syncthreads();

    // Wave 0: 16-way xor-reduce; every lane ends holding all 5 block totals.
    if (t < 64) {
        const int lw = t & 15;
        float Sc0 = red[0][lw], Sc1 = red[1][lw], Sc2 = red[2][lw];
        float Sn0 = red[3][lw], Sn1 = red[4][lw];
        #pragma unroll
        for (int o = 8; o > 0; o >>= 1) {
            Sc0 += __shfl_xor(Sc0, o);
            Sc1 += __shfl_xor(Sc1, o);
            Sc2 += __shfl_xor(Sc2, o);
            Sn0 += __shfl_xor(Sn0, o);
            Sn1 += __shfl_xor(Sn1, o);
        }
        // Lanes 0..4 store component t to partials[t*512 + b]: 5 plain stores.
        if (t < 5) {
            float v = (t == 0) ? Sc0 : (t == 1) ? Sc1 : (t == 2) ? Sc2
                    : (t == 3) ? Sn0 : Sn1;
            partials[t * GN_NBLOCKS + blockIdx.x] = v;
        }
    }
}

__global__ __launch_bounds__(256) void gn_finish(
    const float* __restrict__ partials,
    const float* __restrict__ Wc1,  const float* __restrict__ bc1,
    const float* __restrict__ Wc2,  const float* __restrict__ bc2,
    const float* __restrict__ Wn1,  const float* __restrict__ bn1,
    const float* __restrict__ Wn2,  const float* __restrict__ bn2,
    const float* __restrict__ Wcomb, const float* __restrict__ bcomb,
    const float* __restrict__ Wdeco, const float* __restrict__ bdeco,
    const int* __restrict__ kptr,
    float* __restrict__ out)
{
    const int t = threadIdx.x;

    // 5 components x 512 partials, 2 coalesced loads per thread each.
    float p0 = partials[0 * GN_NBLOCKS + t] + partials[0 * GN_NBLOCKS + 256 + t];
    float p1 = partials[1 * GN_NBLOCKS + t] + partials[1 * GN_NBLOCKS + 256 + t];
    float p2 = partials[2 * GN_NBLOCKS + t] + partials[2 * GN_NBLOCKS + 256 + t];
    float p3 = partials[3 * GN_NBLOCKS + t] + partials[3 * GN_NBLOCKS + 256 + t];
    float p4 = partials[4 * GN_NBLOCKS + t] + partials[4 * GN_NBLOCKS + 256 + t];

    for (int o = 32; o > 0; o >>= 1) {
        p0 += __shfl_down(p0, o);
        p1 += __shfl_down(p1, o);
        p2 += __shfl_down(p2, o);
        p3 += __shfl_down(p3, o);
        p4 += __shfl_down(p4, o);
    }

    __shared__ float red2[5][4];
    if ((t & 63) == 0) {
        const int w = t >> 6;
        red2[0][w] = p0; red2[1][w] = p1; red2[2][w] = p2;
        red2[3][w] = p3; red2[4][w] = p4;
    }
    __syncthreads();

    // ---- Wave-parallel affine epilogue (validated in R7), wave 0 only. ----
    if (t < 64) {
        const int q  = t;
        const int ql = (q < 10) ? q : 0;     // clamped index for safe loads

        // Totals (same-address LDS reads broadcast; free).
        const float Sc0 = red2[0][0] + red2[0][1] + red2[0][2] + red2[0][3];
        const float Sc1 = red2[1][0] + red2[1][1] + red2[1][2] + red2[1][3];
        const float Sc2 = red2[2][0] + red2[2][1] + red2[2][2] + red2[2][3];
        const float Sn0 = red2[3][0] + red2[3][1] + red2[3][2] + red2[3][3];
        const float Sn1 = red2[4][0] + red2[4][1] + red2[4][2] + red2[4][3];

        const float beta = 1.0e6f;   // NODES * bias, applied once

        // tt[q] = Wc1[q,:]*Sc + beta*bc1[q]   (lane q holds tt)
        float tt = Wc1[ql*3+0]*Sc0 + Wc1[ql*3+1]*Sc1 + Wc1[ql*3+2]*Sc2
                 + beta * bc1[ql];
        // H[q] = beta*bc2[q] + sum_p Wc2[q,p] * tt[p]
        float H = beta * bc2[ql];
        #pragma unroll
        for (int p = 0; p < 10; ++p)
            H += Wc2[ql*10+p] * __shfl(tt, p);

        // u[q] = Wn1[q,:]*(Sn/4) + beta*bn1[q]
        float u = Wn1[ql*2+0]*(Sn0*0.25f) + Wn1[ql*2+1]*(Sn1*0.25f)
                + beta * bn1[ql];
        // Mv[q] = beta*bn2[q] + sum_p Wn2[q,p] * u[p]
        float Mv = beta * bn2[ql];
        #pragma unroll
        for (int p = 0; p < 10; ++p)
            Mv += Wn2[ql*10+p] * __shfl(u, p);

        // k comb rounds (lane q holds S[q]).
        const int kk = *kptr;
        float S = H;
        for (int it = 0; it < kk; ++it) {
            float C = beta * bcomb[ql];
            #pragma unroll
            for (int p = 0; p < 10; ++p) {
                C += Wcomb[ql*20 + p]      * __shfl(Mv, p);
                C += Wcomb[ql*20 + 10 + p] * __shfl(S,  p);
            }
            S = C;
        }

        // decode: o = bdeco + sum_q Wdeco[q]*S[q]; plain store.
        float o = bdeco[0];
        #pragma unroll
        for (int p = 0; p < 10; ++p)
            o += Wdeco[p] * __shfl(S, p);

        if (q == 0)
            out[0] = o;
    }
}

extern "C" void kernel_launch(void* const* d_in, const int* in_sizes, int n_in,
                              void* d_out, int out_size, void* d_ws, size_t ws_size,
                              hipStream_t stream) {
    const float* cart  = (const float*)d_in[0];
    const float* neigh = (const float*)d_in[1];
    const float* Wc1   = (const float*)d_in[2];
    const float* bc1   = (const float*)d_in[3];
    const float* Wc2   = (const float*)d_in[4];
    const float* bc2   = (const float*)d_in[5];
    const float* Wn1   = (const float*)d_in[6];
    const float* bn1   = (const float*)d_in[7];
    const float* Wn2   = (const float*)d_in[8];
    const float* bn2   = (const float*)d_in[9];
    const float* Wcomb = (const float*)d_in[10];
    const float* bcomb = (const float*)d_in[11];
    const float* Wdeco = (const float*)d_in[12];
    const float* bdeco = (const float*)d_in[13];
    const int*   kptr  = (const int*)d_in[14];

    float* partials = (float*)d_ws;   // 5 * 512 floats = 10 KB

    gn_reduce<<<GN_NBLOCKS, GN_TPB, 0, stream>>>(cart, neigh, partials);
    gn_finish<<<1, 256, 0, stream>>>(partials,
                                     Wc1, bc1, Wc2, bc2,
                                     Wn1, bn1, Wn2, bn2,
                                     Wcomb, bcomb, Wdeco, bdeco,
                                     kptr, (float*)d_out);
}

// Round 11
// 17.161 us; speedup vs baseline: 1.0319x; 1.0319x over previous
//
#include <hip/hip_runtime.h>

// Problem constants (from the reference file)
#define GN_NODES   1000000
#define GN_TPB     1024
#define GN_NBLOCKS 256
#define GN_T       (GN_TPB * GN_NBLOCKS)   // 262144 threads total

// FINAL (R9 configuration — session best, 17.3 µs):
// Two-kernel, zero-atomic, zero-memset structure:
//   K1 (256x1024): stream-reduce cart+neigh -> 5 block-partial sums ->
//                  plain stores to ws[c*256 + b]  (SoA for coalesced K2 reads)
//   K2 (1x256):    reduce 256 partials per component, apply the (affine)
//                  network once in wave-parallel form, plain-store out[0].
// Kernel-boundary ordering in-stream guarantees visibility of K1's stores
// to K2, so no fences, counters, or atomics are needed anywhere.
//
// Measured A/Bs: 512 blocks flat (+0.4 µs); single-kernel + per-block atomic
// +3.7 µs; fence protocol +85 µs; serial-lane epilogue +5.6 µs.

__global__ __launch_bounds__(GN_TPB) void gn_reduce(
    const float* __restrict__ cart,
    const float* __restrict__ neigh,
    float* __restrict__ partials)
{
    const int t   = threadIdx.x;
    const int tid = blockIdx.x * GN_TPB + t;

    float sx = 0.f, sy = 0.f, sz = 0.f, s0 = 0.f, s1 = 0.f;

    // ---- Streaming reduction (best-measured loop structure). ----
    // cart: 3,000,000 floats = 250,000 chunks of 12 floats (4 nodes).
    // Component pattern within a chunk: x y z x y z x y z x y z.
    const float4* cart4 = reinterpret_cast<const float4*>(cart);
    for (int c = tid; c < 250000; c += GN_T) {
        float4 a = cart4[3 * c + 0];
        float4 b = cart4[3 * c + 1];
        float4 d = cart4[3 * c + 2];
        sx += a.x + a.w + b.z + d.y;
        sy += a.y + b.x + b.w + d.z;
        sz += a.z + b.y + d.x + d.w;
    }

    // neigh: 8,000,000 floats = 2,000,000 float4; components alternate 0,1.
    const float4* n4 = reinterpret_cast<const float4*>(neigh);
    int i = tid;
    for (; i + GN_T < 2000000; i += 2 * GN_T) {
        float4 v = n4[i];
        float4 w = n4[i + GN_T];
        s0 += (v.x + v.z) + (w.x + w.z);
        s1 += (v.y + v.w) + (w.y + w.w);
    }
    if (i < 2000000) {
        float4 v = n4[i];
        s0 += v.x + v.z;
        s1 += v.y + v.w;
    }

    // Wave (64-lane) reduce.
    for (int o = 32; o > 0; o >>= 1) {
        sx += __shfl_down(sx, o);
        sy += __shfl_down(sy, o);
        sz += __shfl_down(sz, o);
        s0 += __shfl_down(s0, o);
        s1 += __shfl_down(s1, o);
    }

    __shared__ float red[5][GN_TPB / 64];
    const int wave = t >> 6;
    if ((t & 63) == 0) {
        red[0][wave] = sx; red[1][wave] = sy; red[2][wave] = sz;
        red[3][wave] = s0; red[4][wave] = s1;
    }
    __syncthreads();

    // Wave 0: 16-way xor-reduce; every lane ends holding all 5 block totals.
    if (t < 64) {
        const int lw = t & 15;
        float Sc0 = red[0][lw], Sc1 = red[1][lw], Sc2 = red[2][lw];
        float Sn0 = red[3][lw], Sn1 = red[4][lw];
        #pragma unroll
        for (int o = 8; o > 0; o >>= 1) {
            Sc0 += __shfl_xor(Sc0, o);
            Sc1 += __shfl_xor(Sc1, o);
            Sc2 += __shfl_xor(Sc2, o);
            Sn0 += __shfl_xor(Sn0, o);
            Sn1 += __shfl_xor(Sn1, o);
        }
        // Lanes 0..4 store component t to partials[t*256 + b]: 5 plain stores.
        if (t < 5) {
            float v = (t == 0) ? Sc0 : (t == 1) ? Sc1 : (t == 2) ? Sc2
                    : (t == 3) ? Sn0 : Sn1;
            partials[t * GN_NBLOCKS + blockIdx.x] = v;
        }
    }
}

__global__ __launch_bounds__(256) void gn_finish(
    const float* __restrict__ partials,
    const float* __restrict__ Wc1,  const float* __restrict__ bc1,
    const float* __restrict__ Wc2,  const float* __restrict__ bc2,
    const float* __restrict__ Wn1,  const float* __restrict__ bn1,
    const float* __restrict__ Wn2,  const float* __restrict__ bn2,
    const float* __restrict__ Wcomb, const float* __restrict__ bcomb,
    const float* __restrict__ Wdeco, const float* __restrict__ bdeco,
    const int* __restrict__ kptr,
    float* __restrict__ out)
{
    const int t = threadIdx.x;

    // 5 coalesced 256-float loads.
    float p0 = partials[0 * GN_NBLOCKS + t];
    float p1 = partials[1 * GN_NBLOCKS + t];
    float p2 = partials[2 * GN_NBLOCKS + t];
    float p3 = partials[3 * GN_NBLOCKS + t];
    float p4 = partials[4 * GN_NBLOCKS + t];

    for (int o = 32; o > 0; o >>= 1) {
        p0 += __shfl_down(p0, o);
        p1 += __shfl_down(p1, o);
        p2 += __shfl_down(p2, o);
        p3 += __shfl_down(p3, o);
        p4 += __shfl_down(p4, o);
    }

    __shared__ float red2[5][4];
    if ((t & 63) == 0) {
        const int w = t >> 6;
        red2[0][w] = p0; red2[1][w] = p1; red2[2][w] = p2;
        red2[3][w] = p3; red2[4][w] = p4;
    }
    __syncthreads();

    // ---- Wave-parallel affine epilogue, wave 0 only. ----
    if (t < 64) {
        const int q  = t;
        const int ql = (q < 10) ? q : 0;     // clamped index for safe loads

        // Totals (same-address LDS reads broadcast; free).
        const float Sc0 = red2[0][0] + red2[0][1] + red2[0][2] + red2[0][3];
        const float Sc1 = red2[1][0] + red2[1][1] + red2[1][2] + red2[1][3];
        const float Sc2 = red2[2][0] + red2[2][1] + red2[2][2] + red2[2][3];
        const float Sn0 = red2[3][0] + red2[3][1] + red2[3][2] + red2[3][3];
        const float Sn1 = red2[4][0] + red2[4][1] + red2[4][2] + red2[4][3];

        const float beta = 1.0e6f;   // NODES * bias, applied once

        // tt[q] = Wc1[q,:]*Sc + beta*bc1[q]   (lane q holds tt)
        float tt = Wc1[ql*3+0]*Sc0 + Wc1[ql*3+1]*Sc1 + Wc1[ql*3+2]*Sc2
                 + beta * bc1[ql];
        // H[q] = beta*bc2[q] + sum_p Wc2[q,p] * tt[p]
        float H = beta * bc2[ql];
        #pragma unroll
        for (int p = 0; p < 10; ++p)
            H += Wc2[ql*10+p] * __shfl(tt, p);

        // u[q] = Wn1[q,:]*(Sn/4) + beta*bn1[q]
        float u = Wn1[ql*2+0]*(Sn0*0.25f) + Wn1[ql*2+1]*(Sn1*0.25f)
                + beta * bn1[ql];
        // Mv[q] = beta*bn2[q] + sum_p Wn2[q,p] * u[p]
        float Mv = beta * bn2[ql];
        #pragma unroll
        for (int p = 0; p < 10; ++p)
            Mv += Wn2[ql*10+p] * __shfl(u, p);

        // k comb rounds (lane q holds S[q]).
        const int kk = *kptr;
        float S = H;
        for (int it = 0; it < kk; ++it) {
            float C = beta * bcomb[ql];
            #pragma unroll
            for (int p = 0; p < 10; ++p) {
                C += Wcomb[ql*20 + p]      * __shfl(Mv, p);
                C += Wcomb[ql*20 + 10 + p] * __shfl(S,  p);
            }
            S = C;
        }

        // decode: o = bdeco + sum_q Wdeco[q]*S[q]; plain store.
        float o = bdeco[0];
        #pragma unroll
        for (int p = 0; p < 10; ++p)
            o += Wdeco[p] * __shfl(S, p);

        if (q == 0)
            out[0] = o;
    }
}

extern "C" void kernel_launch(void* const* d_in, const int* in_sizes, int n_in,
                              void* d_out, int out_size, void* d_ws, size_t ws_size,
                              hipStream_t stream) {
    const float* cart  = (const float*)d_in[0];
    const float* neigh = (const float*)d_in[1];
    const float* Wc1   = (const float*)d_in[2];
    const float* bc1   = (const float*)d_in[3];
    const float* Wc2   = (const float*)d_in[4];
    const float* bc2   = (const float*)d_in[5];
    const float* Wn1   = (const float*)d_in[6];
    const float* bn1   = (const float*)d_in[7];
    const float* Wn2   = (const float*)d_in[8];
    const float* bn2   = (const float*)d_in[9];
    const float* Wcomb = (const float*)d_in[10];
    const float* bcomb = (const float*)d_in[11];
    const float* Wdeco = (const float*)d_in[12];
    const float* bdeco = (const float*)d_in[13];
    const int*   kptr  = (const int*)d_in[14];

    float* partials = (float*)d_ws;   // 5 * 256 floats = 5 KB

    gn_reduce<<<GN_NBLOCKS, GN_TPB, 0, stream>>>(cart, neigh, partials);
    gn_finish<<<1, 256, 0, stream>>>(partials,
                                     Wc1, bc1, Wc2, bc2,
                                     Wn1, bn1, Wn2, bn2,
                                     Wcomb, bcomb, Wdeco, bdeco,
                                     kptr, (float*)d_out);
}

// Round 12
// 16.493 us; speedup vs baseline: 1.0737x; 1.0405x over previous
//
#include <hip/hip_runtime.h>

// Problem constants (from the reference file)
#define GN_NODES   1000000
#define GN_TPB     1024
#define GN_NBLOCKS 256
#define GN_T       (GN_TPB * GN_NBLOCKS)   // 262144 threads total

// R12 = R9 structure (two-kernel, zero-atomic, zero-memset) with K1's loads
// FULLY UNROLLED at compile time: 7 unconditional neigh float4 loads + 1
// conditional + 3 conditional cart loads, all issued before any dependent
// accumulation -> ~8-11 wave-loads in flight per wave (vs ~2 in the
// grid-stride loop). Clean MLP A/B at the optimal 256-block config.
//   neigh: 2,000,000 float4 = 7*262144 + 164992
//   cart : 250,000 chunks of 3 float4 (12 floats = 4 nodes, pattern xyz*4)

__global__ __launch_bounds__(GN_TPB) void gn_reduce(
    const float* __restrict__ cart,
    const float* __restrict__ neigh,
    float* __restrict__ partials)
{
    const int t   = threadIdx.x;
    const int tid = blockIdx.x * GN_TPB + t;

    // ---- Issue ALL loads as independent registers first. ----
    const float4* n4 = reinterpret_cast<const float4*>(neigh);
    float4 n0 = n4[tid + 0 * GN_T];
    float4 n1 = n4[tid + 1 * GN_T];
    float4 n2 = n4[tid + 2 * GN_T];
    float4 n3 = n4[tid + 3 * GN_T];
    float4 n4v = n4[tid + 4 * GN_T];
    float4 n5 = n4[tid + 5 * GN_T];
    float4 n6 = n4[tid + 6 * GN_T];
    float4 n7 = make_float4(0.f, 0.f, 0.f, 0.f);
    if (tid < 2000000 - 7 * GN_T)        // 164992
        n7 = n4[tid + 7 * GN_T];

    float sx = 0.f, sy = 0.f, sz = 0.f;
    const float4* cart4 = reinterpret_cast<const float4*>(cart);
    if (tid < 250000) {
        float4 a = cart4[3 * tid + 0];
        float4 b = cart4[3 * tid + 1];
        float4 d = cart4[3 * tid + 2];
        sx = a.x + a.w + b.z + d.y;
        sy = a.y + b.x + b.w + d.z;
        sz = a.z + b.y + d.x + d.w;
    }

    // neigh components alternate 0,1,0,1 inside each float4.
    float s0 = (n0.x + n0.z) + (n1.x + n1.z) + (n2.x + n2.z) + (n3.x + n3.z)
             + (n4v.x + n4v.z) + (n5.x + n5.z) + (n6.x + n6.z) + (n7.x + n7.z);
    float s1 = (n0.y + n0.w) + (n1.y + n1.w) + (n2.y + n2.w) + (n3.y + n3.w)
             + (n4v.y + n4v.w) + (n5.y + n5.w) + (n6.y + n6.w) + (n7.y + n7.w);

    // Wave (64-lane) reduce.
    for (int o = 32; o > 0; o >>= 1) {
        sx += __shfl_down(sx, o);
        sy += __shfl_down(sy, o);
        sz += __shfl_down(sz, o);
        s0 += __shfl_down(s0, o);
        s1 += __shfl_down(s1, o);
    }

    __shared__ float red[5][GN_TPB / 64];
    const int wave = t >> 6;
    if ((t & 63) == 0) {
        red[0][wave] = sx; red[1][wave] = sy; red[2][wave] = sz;
        red[3][wave] = s0; red[4][wave] = s1;
    }
    __syncthreads();

    // Wave 0: 16-way xor-reduce; every lane ends holding all 5 block totals.
    if (t < 64) {
        const int lw = t & 15;
        float Sc0 = red[0][lw], Sc1 = red[1][lw], Sc2 = red[2][lw];
        float Sn0 = red[3][lw], Sn1 = red[4][lw];
        #pragma unroll
        for (int o = 8; o > 0; o >>= 1) {
            Sc0 += __shfl_xor(Sc0, o);
            Sc1 += __shfl_xor(Sc1, o);
            Sc2 += __shfl_xor(Sc2, o);
            Sn0 += __shfl_xor(Sn0, o);
            Sn1 += __shfl_xor(Sn1, o);
        }
        // Lanes 0..4 store component t to partials[t*256 + b]: 5 plain stores.
        if (t < 5) {
            float v = (t == 0) ? Sc0 : (t == 1) ? Sc1 : (t == 2) ? Sc2
                    : (t == 3) ? Sn0 : Sn1;
            partials[t * GN_NBLOCKS + blockIdx.x] = v;
        }
    }
}

__global__ __launch_bounds__(256) void gn_finish(
    const float* __restrict__ partials,
    const float* __restrict__ Wc1,  const float* __restrict__ bc1,
    const float* __restrict__ Wc2,  const float* __restrict__ bc2,
    const float* __restrict__ Wn1,  const float* __restrict__ bn1,
    const float* __restrict__ Wn2,  const float* __restrict__ bn2,
    const float* __restrict__ Wcomb, const float* __restrict__ bcomb,
    const float* __restrict__ Wdeco, const float* __restrict__ bdeco,
    const int* __restrict__ kptr,
    float* __restrict__ out)
{
    const int t = threadIdx.x;

    // 5 coalesced 256-float loads.
    float p0 = partials[0 * GN_NBLOCKS + t];
    float p1 = partials[1 * GN_NBLOCKS + t];
    float p2 = partials[2 * GN_NBLOCKS + t];
    float p3 = partials[3 * GN_NBLOCKS + t];
    float p4 = partials[4 * GN_NBLOCKS + t];

    for (int o = 32; o > 0; o >>= 1) {
        p0 += __shfl_down(p0, o);
        p1 += __shfl_down(p1, o);
        p2 += __shfl_down(p2, o);
        p3 += __shfl_down(p3, o);
        p4 += __shfl_down(p4, o);
    }

    __shared__ float red2[5][4];
    if ((t & 63) == 0) {
        const int w = t >> 6;
        red2[0][w] = p0; red2[1][w] = p1; red2[2][w] = p2;
        red2[3][w] = p3; red2[4][w] = p4;
    }
    __syncthreads();

    // ---- Wave-parallel affine epilogue, wave 0 only. ----
    if (t < 64) {
        const int q  = t;
        const int ql = (q < 10) ? q : 0;     // clamped index for safe loads

        // Totals (same-address LDS reads broadcast; free).
        const float Sc0 = red2[0][0] + red2[0][1] + red2[0][2] + red2[0][3];
        const float Sc1 = red2[1][0] + red2[1][1] + red2[1][2] + red2[1][3];
        const float Sc2 = red2[2][0] + red2[2][1] + red2[2][2] + red2[2][3];
        const float Sn0 = red2[3][0] + red2[3][1] + red2[3][2] + red2[3][3];
        const float Sn1 = red2[4][0] + red2[4][1] + red2[4][2] + red2[4][3];

        const float beta = 1.0e6f;   // NODES * bias, applied once

        // tt[q] = Wc1[q,:]*Sc + beta*bc1[q]   (lane q holds tt)
        float tt = Wc1[ql*3+0]*Sc0 + Wc1[ql*3+1]*Sc1 + Wc1[ql*3+2]*Sc2
                 + beta * bc1[ql];
        // H[q] = beta*bc2[q] + sum_p Wc2[q,p] * tt[p]
        float H = beta * bc2[ql];
        #pragma unroll
        for (int p = 0; p < 10; ++p)
            H += Wc2[ql*10+p] * __shfl(tt, p);

        // u[q] = Wn1[q,:]*(Sn/4) + beta*bn1[q]
        float u = Wn1[ql*2+0]*(Sn0*0.25f) + Wn1[ql*2+1]*(Sn1*0.25f)
                + beta * bn1[ql];
        // Mv[q] = beta*bn2[q] + sum_p Wn2[q,p] * u[p]
        float Mv = beta * bn2[ql];
        #pragma unroll
        for (int p = 0; p < 10; ++p)
            Mv += Wn2[ql*10+p] * __shfl(u, p);

        // k comb rounds (lane q holds S[q]).
        const int kk = *kptr;
        float S = H;
        for (int it = 0; it < kk; ++it) {
            float C = beta * bcomb[ql];
            #pragma unroll
            for (int p = 0; p < 10; ++p) {
                C += Wcomb[ql*20 + p]      * __shfl(Mv, p);
                C += Wcomb[ql*20 + 10 + p] * __shfl(S,  p);
            }
            S = C;
        }

        // decode: o = bdeco + sum_q Wdeco[q]*S[q]; plain store.
        float o = bdeco[0];
        #pragma unroll
        for (int p = 0; p < 10; ++p)
            o += Wdeco[p] * __shfl(S, p);

        if (q == 0)
            out[0] = o;
    }
}

extern "C" void kernel_launch(void* const* d_in, const int* in_sizes, int n_in,
                              void* d_out, int out_size, void* d_ws, size_t ws_size,
                              hipStream_t stream) {
    const float* cart  = (const float*)d_in[0];
    const float* neigh = (const float*)d_in[1];
    const float* Wc1   = (const float*)d_in[2];
    const float* bc1   = (const float*)d_in[3];
    const float* Wc2   = (const float*)d_in[4];
    const float* bc2   = (const float*)d_in[5];
    const float* Wn1   = (const float*)d_in[6];
    const float* bn1   = (const float*)d_in[7];
    const float* Wn2   = (const float*)d_in[8];
    const float* bn2   = (const float*)d_in[9];
    const float* Wcomb = (const float*)d_in[10];
    const float* bcomb = (const float*)d_in[11];
    const float* Wdeco = (const float*)d_in[12];
    const float* bdeco = (const float*)d_in[13];
    const int*   kptr  = (const int*)d_in[14];

    float* partials = (float*)d_ws;   // 5 * 256 floats = 5 KB

    gn_reduce<<<GN_NBLOCKS, GN_TPB, 0, stream>>>(cart, neigh, partials);
    gn_finish<<<1, 256, 0, stream>>>(partials,
                                     Wc1, bc1, Wc2, bc2,
                                     Wn1, bn1, Wn2, bn2,
                                     Wcomb, bcomb, Wdeco, bdeco,
                                     kptr, (float*)d_out);
}